// Round 10
// baseline (119.725 us; speedup 1.0000x reference)
//
#include <hip/hip_runtime.h>
#include <math.h>

#define DD 128

__device__ __forceinline__ unsigned bf16rne(float f) {
    unsigned u = __float_as_uint(f);
    return (u + 0x7FFFu + ((u >> 16) & 1u)) >> 16;
}
__device__ __forceinline__ float2 bf2f(unsigned u) {
    float2 r;
    r.x = __uint_as_float(u << 16);
    r.y = __uint_as_float(u & 0xFFFF0000u);
    return r;
}

// ---- mark live nodes into a BITMASK (6.25 KB -> L1-resident) ---------------
__global__ __launch_bounds__(256) void k_mark(const int* __restrict__ src1,
                                              const int* __restrict__ dst1,
                                              int E1, int BS,
                                              unsigned* __restrict__ mb) {
    int base = blockIdx.x * 1024 + threadIdx.x;
    #pragma unroll
    for (int j = 0; j < 4; ++j) {
        int e = base + j * 256;
        if (e < E1) {
            int d = dst1[e];
            if (d < BS) {
                int s = src1[e];
                atomicOr(&mb[s >> 5], 1u << (s & 31));
            }
        }
    }
    int g = blockIdx.x * 256 + threadIdx.x;
    if (g < BS) atomicOr(&mb[g >> 5], 1u << (g & 31));
}

// ---- F1: linear0 (32-row tiles, b128 LDS reads) || filtered hist || mscanA -
__global__ __launch_bounds__(256) void k_histlin(
        const float* __restrict__ x, const float* __restrict__ w,
        const float* __restrict__ b, unsigned* __restrict__ y, int nrows,
        int gLin, int gH0, int gH1,
        const int* __restrict__ dst0, int E0,
        const int* __restrict__ dst1, int E1, int BS,
        const unsigned* __restrict__ mb, int* __restrict__ cnt,
        int* __restrict__ rank, int N,
        int W, int* __restrict__ mex, int* __restrict__ mbsum) {
    __shared__ float  xs[32][DD];     // 16 KB
    __shared__ float4 wb[32][32];     // 16 KB

    if (blockIdx.x >= gLin) {
        int role = blockIdx.x - gLin;
        if (role < gH0) {                       // hist conv0 (live dst only)
            int base = role * 1024 + threadIdx.x;
            #pragma unroll
            for (int j = 0; j < 4; ++j) {
                int e = base + j * 256;
                if (e < E0) {
                    int d = dst0[e];
                    if ((mb[d >> 5] >> (d & 31)) & 1u)
                        rank[e] = atomicAdd(&cnt[d], 1);
                }
            }
        } else if (role < gH0 + gH1) {          // hist conv1 (dst < BS)
            int base = (role - gH0) * 1024 + threadIdx.x;
            #pragma unroll
            for (int j = 0; j < 4; ++j) {
                int e = base + j * 256;
                if (e < E1) {
                    int d = dst1[e];
                    if (d < BS) rank[E0 + e] = atomicAdd(&cnt[N + d], 1);
                }
            }
        } else {                                // mscanA over mask words
            __shared__ int s[256];
            int idx = (role - gH0 - gH1) * 256 + threadIdx.x;
            int v = (idx < W) ? __popc(mb[idx]) : 0;
            s[threadIdx.x] = v;
            __syncthreads();
            for (int o = 1; o < 256; o <<= 1) {
                int t = (threadIdx.x >= o) ? s[threadIdx.x - o] : 0;
                __syncthreads();
                s[threadIdx.x] += t;
                __syncthreads();
            }
            if (idx < W) mex[idx] = s[threadIdx.x] - v;
            if (threadIdx.x == 255) mbsum[role - gH0 - gH1] = s[255];
        }
        return;
    }

    // ---- linear: 32 rows x 128 cols, vectorized LDS reads ----
    int rbase = blockIdx.x * 32;
    for (int i = threadIdx.x; i < 32 * 32; i += 256) {
        int r = rbase + (i >> 5);
        float4 v = make_float4(0.f, 0.f, 0.f, 0.f);
        if (r < nrows) v = ((const float4*)x)[(size_t)r * 32 + (i & 31)];
        *(float4*)&xs[i >> 5][(i & 31) * 4] = v;
    }
    int g  = threadIdx.x >> 5;
    int cg = threadIdx.x & 31;
    float4 bb = ((const float4*)b)[cg];
    float4 acc[4];
    #pragma unroll
    for (int r = 0; r < 4; ++r) acc[r] = bb;
    const float4* wv = (const float4*)w;
    for (int kc = 0; kc < DD; kc += 32) {
        __syncthreads();
        for (int i = threadIdx.x; i < 32 * 32; i += 256)
            wb[i >> 5][i & 31] = wv[(size_t)(kc + (i >> 5)) * 32 + (i & 31)];
        __syncthreads();
        #pragma unroll
        for (int kk = 0; kk < 32; kk += 4) {
            float xr0[4], xr1[4], xr2[4], xr3[4];
            *(float4*)xr0 = *(const float4*)&xs[g * 4 + 0][kc + kk];
            *(float4*)xr1 = *(const float4*)&xs[g * 4 + 1][kc + kk];
            *(float4*)xr2 = *(const float4*)&xs[g * 4 + 2][kc + kk];
            *(float4*)xr3 = *(const float4*)&xs[g * 4 + 3][kc + kk];
            #pragma unroll
            for (int q = 0; q < 4; ++q) {
                float4 wk = wb[kk + q][cg];
                acc[0].x += xr0[q] * wk.x; acc[0].y += xr0[q] * wk.y;
                acc[0].z += xr0[q] * wk.z; acc[0].w += xr0[q] * wk.w;
                acc[1].x += xr1[q] * wk.x; acc[1].y += xr1[q] * wk.y;
                acc[1].z += xr1[q] * wk.z; acc[1].w += xr1[q] * wk.w;
                acc[2].x += xr2[q] * wk.x; acc[2].y += xr2[q] * wk.y;
                acc[2].z += xr2[q] * wk.z; acc[2].w += xr2[q] * wk.w;
                acc[3].x += xr3[q] * wk.x; acc[3].y += xr3[q] * wk.y;
                acc[3].z += xr3[q] * wk.z; acc[3].w += xr3[q] * wk.w;
            }
        }
    }
    #pragma unroll
    for (int r = 0; r < 4; ++r) {
        int row = rbase + g * 4 + r;
        if (row < nrows) {
            uint2 p;
            p.x = bf16rne(acc[r].x) | (bf16rne(acc[r].y) << 16);
            p.y = bf16rne(acc[r].z) | (bf16rne(acc[r].w) << 16);
            ((uint2*)y)[(size_t)row * 32 + cg] = p;
        }
    }
}

// ---- K3: scanA over cnt (blocks 0..gS-1) + tiny serial mscanB (block gS) ---
__global__ __launch_bounds__(256) void k_scanA2(const int* __restrict__ cnt, int n,
                                                int* __restrict__ ex,
                                                int* __restrict__ bsum, int gS,
                                                int* __restrict__ mbsum, int nMs) {
    if (blockIdx.x == gS) {
        if (threadIdx.x == 0) {
            int run = 0;
            for (int i = 0; i < nMs; ++i) { int t = mbsum[i]; mbsum[i] = run; run += t; }
        }
        return;
    }
    __shared__ int s[256];
    int idx = blockIdx.x * 256 + threadIdx.x;
    int v = (idx < n) ? cnt[idx] : 0;
    s[threadIdx.x] = v;
    __syncthreads();
    for (int o = 1; o < 256; o <<= 1) {
        int t = (threadIdx.x >= o) ? s[threadIdx.x - o] : 0;
        __syncthreads();
        s[threadIdx.x] += t;
        __syncthreads();
    }
    if (idx < n) ex[idx] = s[threadIdx.x] - v;
    if (threadIdx.x == 255) bsum[blockIdx.x] = s[255];
}

// ---- K4: mscanC (livelist, blocks 0..gMs-1) + scanB over bsum (block gMs) --
__global__ __launch_bounds__(256) void k_mscanC2(const unsigned* __restrict__ mb,
                                                 int W,
                                                 const int* __restrict__ mex,
                                                 const int* __restrict__ mbsum,
                                                 int* __restrict__ livelist,
                                                 int* __restrict__ nLive,
                                                 int gMs,
                                                 int* __restrict__ bsum, int nb) {
    if (blockIdx.x == gMs) {
        __shared__ int s[256];
        int v = (threadIdx.x < nb) ? bsum[threadIdx.x] : 0;
        s[threadIdx.x] = v;
        __syncthreads();
        for (int o = 1; o < 256; o <<= 1) {
            int t = (threadIdx.x >= o) ? s[threadIdx.x - o] : 0;
            __syncthreads();
            s[threadIdx.x] += t;
            __syncthreads();
        }
        if (threadIdx.x < nb) bsum[threadIdx.x] = s[threadIdx.x] - v;
        return;
    }
    int idx = blockIdx.x * 256 + threadIdx.x;
    if (idx < W) {
        unsigned word = mb[idx];
        int base = mex[idx] + mbsum[blockIdx.x];
        unsigned wt = word;
        while (wt) {
            int bit = __ffs(wt) - 1;
            livelist[base + __popc(word & ((1u << bit) - 1u))] = idx * 32 + bit;
            wt &= wt - 1;
        }
        if (idx == W - 1) *nLive = base + __popc(word);
    }
}

// ---- F2: CSR fill for live conv0 edges (rowptr computed on the fly) --------
__global__ __launch_bounds__(256) void k_fill0(const int* __restrict__ src0,
                                               const int* __restrict__ dst0, int E0,
                                               const unsigned* __restrict__ mb,
                                               const int* __restrict__ ex,
                                               const int* __restrict__ bsum,
                                               const int* __restrict__ rank,
                                               int* __restrict__ ssrc) {
    int base = blockIdx.x * 1024 + threadIdx.x;
    #pragma unroll
    for (int j = 0; j < 4; ++j) {
        int e = base + j * 256;
        if (e < E0) {
            int d = dst0[e];
            if ((mb[d >> 5] >> (d & 31)) & 1u)
                ssrc[ex[d] + bsum[d >> 8] + rank[e]] = src0[e];
        }
    }
}

// ---- agg0 (mask-gated, all nodes) with leading conv1-fill blocks -----------
__global__ __launch_bounds__(256) void k_aggL(const unsigned* __restrict__ xl,
                                              const int* __restrict__ ex,
                                              const int* __restrict__ bsum,
                                              const int* __restrict__ cnt,
                                              const int* __restrict__ ssrc,
                                              const float* __restrict__ att,
                                              const float* __restrict__ bias,
                                              float* __restrict__ out,
                                              const unsigned* __restrict__ mb,
                                              int n, int gF1,
                                              const int* __restrict__ src1,
                                              const int* __restrict__ dst1, int E1,
                                              int BS, int E0, int N,
                                              const int* __restrict__ rank,
                                              int* __restrict__ ssrcW) {
    if (blockIdx.x < gF1) {
        int base = blockIdx.x * 1024 + threadIdx.x;
        #pragma unroll
        for (int j = 0; j < 4; ++j) {
            int e = base + j * 256;
            if (e < E1) {
                int d = dst1[e];
                if (d < BS) {
                    int key = N + d;
                    ssrcW[ex[key] + bsum[key >> 8] + rank[E0 + e]] = src1[e];
                }
            }
        }
        return;
    }
    int node = __builtin_amdgcn_readfirstlane((blockIdx.x - gF1) * 4 +
                                              (threadIdx.x >> 6));
    if (node >= n) return;
    if (!((mb[node >> 5] >> (node & 31)) & 1u)) return;
    int lane = threadIdx.x & 63;
    float2 attv = *(const float2*)&att[lane * 2];
    float2 xd = bf2f(xl[(size_t)node * 64 + lane]);
    int rs  = ex[node] + bsum[node >> 8];
    int deg = cnt[node];

    float m = -3.4e38f, den = 0.f, accx = 0.f, accy = 0.f;
    int sA = (deg > 0) ? ssrc[rs] : 0;
    int sB = (deg > 1) ? ssrc[rs + 1] : 0;
    unsigned uA = xl[(size_t)sA * 64 + lane];
    unsigned uB = xl[(size_t)sB * 64 + lane];

    int k = 0;
    for (; k + 1 < deg; k += 2) {
        int sC = (k + 2 < deg) ? ssrc[rs + k + 2] : 0;
        int sD = (k + 3 < deg) ? ssrc[rs + k + 3] : 0;
        unsigned uC = xl[(size_t)sC * 64 + lane];
        unsigned uD = xl[(size_t)sD * 64 + lane];
        float2 vA = bf2f(uA), vB = bf2f(uB);

        float tx = xd.x + vA.x, ty = xd.y + vA.y;
        tx = tx > 0.f ? tx : 0.2f * tx;
        ty = ty > 0.f ? ty : 0.2f * ty;
        float l0 = tx * attv.x + ty * attv.y;
        tx = xd.x + vB.x; ty = xd.y + vB.y;
        tx = tx > 0.f ? tx : 0.2f * tx;
        ty = ty > 0.f ? ty : 0.2f * ty;
        float l1 = tx * attv.x + ty * attv.y;
        #pragma unroll
        for (int o = 8; o; o >>= 1) {
            l0 += __shfl_xor(l0, o, 64);
            l1 += __shfl_xor(l1, o, 64);
        }
        float mn = fmaxf(fmaxf(m, l0), l1);
        float corr = __expf(m - mn);
        float w0 = __expf(l0 - mn);
        float w1 = __expf(l1 - mn);
        den  = den  * corr + w0 + w1;
        accx = accx * corr + w0 * vA.x + w1 * vB.x;
        accy = accy * corr + w0 * vA.y + w1 * vB.y;
        m = mn;
        sA = sC; sB = sD; uA = uC; uB = uD;
    }
    if (k < deg) {
        float2 vA = bf2f(uA);
        float tx = xd.x + vA.x, ty = xd.y + vA.y;
        tx = tx > 0.f ? tx : 0.2f * tx;
        ty = ty > 0.f ? ty : 0.2f * ty;
        float l0 = tx * attv.x + ty * attv.y;
        #pragma unroll
        for (int o = 8; o; o >>= 1) l0 += __shfl_xor(l0, o, 64);
        float mn = fmaxf(m, l0);
        float corr = __expf(m - mn);
        float w0 = __expf(l0 - mn);
        den  = den  * corr + w0;
        accx = accx * corr + w0 * vA.x;
        accy = accy * corr + w0 * vA.y;
    }

    float inv = (deg > 0) ? 1.f / den : 0.f;
    float2 o2;
    o2.x = accx * inv + bias[lane * 2];
    o2.y = accy * inv + bias[lane * 2 + 1];
    *(float2*)&out[(size_t)node * DD + lane * 2] = o2;
}

// ---- lin1 over livelist rows only (gelu on input, vectorized LDS reads) ----
__global__ __launch_bounds__(256) void k_linC(const float* __restrict__ x,
                                              const float* __restrict__ w,
                                              const float* __restrict__ b,
                                              unsigned* __restrict__ y,
                                              const int* __restrict__ livelist,
                                              const int* __restrict__ nLive) {
    __shared__ float  xs[32][DD];
    __shared__ float4 wb[32][32];
    int nL = *nLive;
    int lbase = blockIdx.x * 32;
    if (lbase >= nL) return;

    for (int i = threadIdx.x; i < 32 * 32; i += 256) {
        int li = lbase + (i >> 5);
        float4 v = make_float4(0.f, 0.f, 0.f, 0.f);
        if (li < nL) {
            int r = livelist[li];
            v = ((const float4*)x)[(size_t)r * 32 + (i & 31)];
            v.x = 0.5f * v.x * (1.f + erff(v.x * 0.70710678f));
            v.y = 0.5f * v.y * (1.f + erff(v.y * 0.70710678f));
            v.z = 0.5f * v.z * (1.f + erff(v.z * 0.70710678f));
            v.w = 0.5f * v.w * (1.f + erff(v.w * 0.70710678f));
        }
        *(float4*)&xs[i >> 5][(i & 31) * 4] = v;
    }
    int g  = threadIdx.x >> 5;
    int cg = threadIdx.x & 31;
    float4 bb = ((const float4*)b)[cg];
    float4 acc[4];
    #pragma unroll
    for (int r = 0; r < 4; ++r) acc[r] = bb;
    const float4* wv = (const float4*)w;
    for (int kc = 0; kc < DD; kc += 32) {
        __syncthreads();
        for (int i = threadIdx.x; i < 32 * 32; i += 256)
            wb[i >> 5][i & 31] = wv[(size_t)(kc + (i >> 5)) * 32 + (i & 31)];
        __syncthreads();
        #pragma unroll
        for (int kk = 0; kk < 32; kk += 4) {
            float xr0[4], xr1[4], xr2[4], xr3[4];
            *(float4*)xr0 = *(const float4*)&xs[g * 4 + 0][kc + kk];
            *(float4*)xr1 = *(const float4*)&xs[g * 4 + 1][kc + kk];
            *(float4*)xr2 = *(const float4*)&xs[g * 4 + 2][kc + kk];
            *(float4*)xr3 = *(const float4*)&xs[g * 4 + 3][kc + kk];
            #pragma unroll
            for (int q = 0; q < 4; ++q) {
                float4 wk = wb[kk + q][cg];
                acc[0].x += xr0[q] * wk.x; acc[0].y += xr0[q] * wk.y;
                acc[0].z += xr0[q] * wk.z; acc[0].w += xr0[q] * wk.w;
                acc[1].x += xr1[q] * wk.x; acc[1].y += xr1[q] * wk.y;
                acc[1].z += xr1[q] * wk.z; acc[1].w += xr1[q] * wk.w;
                acc[2].x += xr2[q] * wk.x; acc[2].y += xr2[q] * wk.y;
                acc[2].z += xr2[q] * wk.z; acc[2].w += xr2[q] * wk.w;
                acc[3].x += xr3[q] * wk.x; acc[3].y += xr3[q] * wk.y;
                acc[3].z += xr3[q] * wk.z; acc[3].w += xr3[q] * wk.w;
            }
        }
    }
    #pragma unroll
    for (int r = 0; r < 4; ++r) {
        int li = lbase + g * 4 + r;
        if (li < nL) {
            int row = livelist[li];
            uint2 p;
            p.x = bf16rne(acc[r].x) | (bf16rne(acc[r].y) << 16);
            p.y = bf16rne(acc[r].z) | (bf16rne(acc[r].w) << 16);
            ((uint2*)y)[(size_t)row * 32 + cg] = p;
        }
    }
}

// ---- agg1 (nodes [0,BS)) fused with linear+LayerNorm head -------------------
__global__ __launch_bounds__(256) void k_agg1head(
        const unsigned* __restrict__ xl,
        const int* __restrict__ ex, const int* __restrict__ bsum,
        const int* __restrict__ cnt, const int* __restrict__ ssrc,
        const float* __restrict__ att, const float* __restrict__ bias,
        const float* __restrict__ wout, const float* __restrict__ bout,
        const float* __restrict__ gamma, const float* __restrict__ beta,
        float* __restrict__ yout, int N, int BS) {
    __shared__ float xrow[4][DD];
    int wid  = threadIdx.x >> 6;
    int lane = threadIdx.x & 63;
    int node = blockIdx.x * 4 + wid;
    if (node >= BS) return;
    float2 attv = *(const float2*)&att[lane * 2];
    float2 xd = bf2f(xl[(size_t)node * 64 + lane]);
    int key = N + node;
    int rs  = ex[key] + bsum[key >> 8];
    int deg = cnt[key];

    float m = -3.4e38f, den = 0.f, accx = 0.f, accy = 0.f;
    int sA = (deg > 0) ? ssrc[rs] : 0;
    int sB = (deg > 1) ? ssrc[rs + 1] : 0;
    unsigned uA = xl[(size_t)sA * 64 + lane];
    unsigned uB = xl[(size_t)sB * 64 + lane];

    int k = 0;
    for (; k + 1 < deg; k += 2) {
        int sC = (k + 2 < deg) ? ssrc[rs + k + 2] : 0;
        int sD = (k + 3 < deg) ? ssrc[rs + k + 3] : 0;
        unsigned uC = xl[(size_t)sC * 64 + lane];
        unsigned uD = xl[(size_t)sD * 64 + lane];
        float2 vA = bf2f(uA), vB = bf2f(uB);
        float tx = xd.x + vA.x, ty = xd.y + vA.y;
        tx = tx > 0.f ? tx : 0.2f * tx;
        ty = ty > 0.f ? ty : 0.2f * ty;
        float l0 = tx * attv.x + ty * attv.y;
        tx = xd.x + vB.x; ty = xd.y + vB.y;
        tx = tx > 0.f ? tx : 0.2f * tx;
        ty = ty > 0.f ? ty : 0.2f * ty;
        float l1 = tx * attv.x + ty * attv.y;
        #pragma unroll
        for (int o = 8; o; o >>= 1) {
            l0 += __shfl_xor(l0, o, 64);
            l1 += __shfl_xor(l1, o, 64);
        }
        float mn = fmaxf(fmaxf(m, l0), l1);
        float corr = __expf(m - mn);
        float w0 = __expf(l0 - mn);
        float w1 = __expf(l1 - mn);
        den  = den  * corr + w0 + w1;
        accx = accx * corr + w0 * vA.x + w1 * vB.x;
        accy = accy * corr + w0 * vA.y + w1 * vB.y;
        m = mn;
        sA = sC; sB = sD; uA = uC; uB = uD;
    }
    if (k < deg) {
        float2 vA = bf2f(uA);
        float tx = xd.x + vA.x, ty = xd.y + vA.y;
        tx = tx > 0.f ? tx : 0.2f * tx;
        ty = ty > 0.f ? ty : 0.2f * ty;
        float l0 = tx * attv.x + ty * attv.y;
        #pragma unroll
        for (int o = 8; o; o >>= 1) l0 += __shfl_xor(l0, o, 64);
        float mn = fmaxf(m, l0);
        float corr = __expf(m - mn);
        float w0 = __expf(l0 - mn);
        den  = den  * corr + w0;
        accx = accx * corr + w0 * vA.x;
        accy = accy * corr + w0 * vA.y;
    }

    float inv = (deg > 0) ? 1.f / den : 0.f;
    float2 o2;
    o2.x = accx * inv + bias[lane * 2];
    o2.y = accy * inv + bias[lane * 2 + 1];

    xrow[wid][lane * 2]     = o2.x;
    xrow[wid][lane * 2 + 1] = o2.y;
    float2 acc2 = *(const float2*)&bout[lane * 2];
    __syncthreads();
    #pragma unroll 4
    for (int kk = 0; kk < DD; ++kk) {
        float xv = xrow[wid][kk];
        float2 wv2 = *(const float2*)&wout[(size_t)kk * DD + lane * 2];
        acc2.x += xv * wv2.x;
        acc2.y += xv * wv2.y;
    }
    float s = acc2.x + acc2.y;
    #pragma unroll
    for (int o = 32; o; o >>= 1) s += __shfl_xor(s, o, 64);
    float mean = s * (1.f / 128.f);
    float dx = acc2.x - mean, dy = acc2.y - mean;
    float s2 = dx * dx + dy * dy;
    #pragma unroll
    for (int o = 32; o; o >>= 1) s2 += __shfl_xor(s2, o, 64);
    float rstd = rsqrtf(s2 * (1.f / 128.f) + 1e-12f);
    float2 g2 = *(const float2*)&gamma[lane * 2];
    float2 b2 = *(const float2*)&beta[lane * 2];
    float2 yo;
    yo.x = dx * rstd * g2.x + b2.x;
    yo.y = dy * rstd * g2.y + b2.y;
    *(float2*)&yout[(size_t)node * DD + lane * 2] = yo;
}

extern "C" void kernel_launch(void* const* d_in, const int* in_sizes, int n_in,
                              void* d_out, int out_size, void* d_ws, size_t ws_size,
                              hipStream_t stream) {
    const float* embs  = (const float*)d_in[0];
    const float* w0    = (const float*)d_in[1];
    const float* b0    = (const float*)d_in[2];
    const float* att0  = (const float*)d_in[3];
    const float* bias0 = (const float*)d_in[4];
    const float* w1    = (const float*)d_in[5];
    const float* b1    = (const float*)d_in[6];
    const float* att1  = (const float*)d_in[7];
    const float* bias1 = (const float*)d_in[8];
    const float* wout  = (const float*)d_in[9];
    const float* bout  = (const float*)d_in[10];
    const float* gamma = (const float*)d_in[11];
    const float* beta  = (const float*)d_in[12];
    const int* ei0 = (const int*)d_in[13];
    const int* ei1 = (const int*)d_in[14];

    int N  = in_sizes[0] / DD;
    int E0 = in_sizes[13] / 2;
    int E1 = in_sizes[14] / 2;
    int BS = out_size / DD;
    int n2 = N + BS;
    int W  = (N + 31) / 32;

    // ---- workspace carve-up ----
    unsigned* xl   = (unsigned*)d_ws;                      // N*64 (bf16 pairs)
    float* out     = (float*)(xl + (size_t)N * 64);        // N*128 f32
    int* ssrc      = (int*)(out + (size_t)N * DD);         // E0+E1
    int* rank      = ssrc + (E0 + E1);                     // E0+E1
    int* cnt       = rank + (E0 + E1);                     // n2   (memset)
    unsigned* mb   = (unsigned*)(cnt + n2);                // W+32 (memset, adjacent)
    int* ex        = (int*)(mb + W + 32);                  // n2
    int* bsum      = ex + n2;                              // 256
    int* mex       = bsum + 256;                           // W
    int* mbsum     = mex + W;                              // 32
    int* livelist  = mbsum + 32;                           // N
    int* nLive     = livelist + N;                         // 1

    int gH0  = (E0 + 1023) / 1024;
    int gH1  = (E1 + 1023) / 1024;
    int gLin = (N + 31) / 32;
    int gS   = (n2 + 255) / 256;
    int gMs  = (W + 255) / 256;

    // 1. zero cnt + maskbits (contiguous)
    hipMemsetAsync(cnt, 0, ((size_t)n2 + W + 32) * sizeof(int), stream);
    // 2. mark live nodes (bitmask)
    k_mark<<<gH1, 256, 0, stream>>>(ei1, ei1 + E1, E1, BS, mb);
    // 3. F1: linear0 || filtered hist (both convs) || mscanA
    k_histlin<<<gLin + gH0 + gH1 + gMs, 256, 0, stream>>>(
        embs, w0, b0, xl, N, gLin, gH0, gH1,
        ei0 + E0, E0, ei1 + E1, E1, BS, mb, cnt, rank, N, W, mex, mbsum);
    // 4. CSR scanA + mscanB
    k_scanA2<<<gS + 1, 256, 0, stream>>>(cnt, n2, ex, bsum, gS, mbsum, gMs);
    // 5. livelist compaction + CSR scanB
    k_mscanC2<<<gMs + 1, 256, 0, stream>>>(mb, W, mex, mbsum, livelist, nLive,
                                           gMs, bsum, gS);
    // 6. F2: fill conv0's live edges (rowptr on the fly)
    k_fill0<<<gH0, 256, 0, stream>>>(ei0, ei0 + E0, E0, mb, ex, bsum, rank, ssrc);
    // 7. agg0 (mask-gated) with conv1-fill hidden in leading blocks
    k_aggL<<<gH1 + (N + 3) / 4, 256, 0, stream>>>(
        xl, ex, bsum, cnt, ssrc, att0, bias0, out, mb, N, gH1,
        ei1, ei1 + E1, E1, BS, E0, N, rank, ssrc);
    // 8. lin1 over live rows only (gelu)
    k_linC<<<gLin, 256, 0, stream>>>(out, w1, b1, xl, livelist, nLive);
    // 9. agg1 (dst<BS) + head
    k_agg1head<<<(BS + 3) / 4, 256, 0, stream>>>(
        xl, ex, bsum, cnt, ssrc, att1, bias1,
        wout, bout, gamma, beta, (float*)d_out, N, BS);
}